// Round 3
// baseline (794.011 us; speedup 1.0000x reference)
//
#include <hip/hip_runtime.h>
#include <hip/hip_bf16.h>
#include <stdint.h>

// Problem constants
#define Bsz 2048
#define Ssz 200
#define Dsz 128
#define Hsz 4
#define SP  224   // padded S for score buffer

typedef __attribute__((ext_vector_type(8))) short short8;
typedef __attribute__((ext_vector_type(4))) float f32x4;
typedef unsigned short ushort_t;
typedef unsigned int uint_t;

// ---- LDS byte offsets (2 blocks/CU: total must stay <= 80 KB) ----
#define H1C_OFF    0        // [112][256] bf16 swz        57,344
#define SCW_OFF    57344    // [4][224] f32                3,584
#define C1S_OFF    60928    // [256] f32                   1,024
#define QS_OFF     61952    // [128] f32                     512
#define B2S_OFF    62464    // [128] f32                     512
#define W3S_OFF    62976    // [128] f32                     512
#define MASK_OFF   63488    // [224] int                     896
#define COMB_OFF   64384    // [128] f32                     512
#define PO_OFF     64896    // [4][128] f32                2,048
#define A1S_OFF    66944
#define A2S_OFF    66960
#define B3S_OFF    66976
#define SMEM_BYTES 66992

__device__ __forceinline__ ushort_t f2bf(float x) {
    union { float f; uint_t u; } v; v.f = x;
    uint_t u = v.u;
    u += 0x7FFFu + ((u >> 16) & 1u);   // round-to-nearest-even
    return (ushort_t)(u >> 16);
}

// ---------- prep: fold W1, transpose Wo, cast W2 ----------
__global__ void prep_kernel(const float* __restrict__ W1, const float* __restrict__ W2,
                            const float* __restrict__ Wo,
                            float* __restrict__ W1sum, float* __restrict__ W1c,
                            float* __restrict__ W1diffT, float* __restrict__ WoT,
                            ushort_t* __restrict__ W2bf) {
    int i = blockIdx.x * blockDim.x + threadIdx.x;
    if (i < 32768) {                       // n in [0,256), j in [0,128)
        int n = i >> 7, j = i & 127;
        float a  = W1[n * 512 + j];        // keys part
        float dd = W1[n * 512 + 384 + j];  // (k - q) part
        W1sum[i] = a + dd;                 // coeff of k
        W1c[i]   = W1[n * 512 + 256 + j];  // coeff of k*q
        W1diffT[j * 256 + n] = W1[n * 512 + 128 + j] - dd;  // coeff of q (transposed)
    }
    if (i < 16384) {                       // WoT[j][d] = Wo[d][j]
        int j = i >> 7, d = i & 127;
        WoT[i] = Wo[d * 128 + j];
    }
    if (i < 8192) W2bf[i] = f2bf(W2[i]);   // flat [h][e][k], k fastest
}

// ---------- fused main kernel: one block per batch element, 2 blocks/CU ----------
__launch_bounds__(512, 4)
__global__ void attn_kernel(const float* __restrict__ query, const float* __restrict__ keys,
                            const int* __restrict__ kmask,
                            const float* __restrict__ a1, const float* __restrict__ b2,
                            const float* __restrict__ a2, const float* __restrict__ W3,
                            const float* __restrict__ b3, const float* __restrict__ b1,
                            const float* __restrict__ bo,
                            const float* __restrict__ W1sum, const float* __restrict__ W1c,
                            const float* __restrict__ W1diffT,
                            const float* __restrict__ WoT, const ushort_t* __restrict__ W2bf,
                            float* __restrict__ out) {
    extern __shared__ char smem[];
    const int tid = threadIdx.x;
    const int bb  = blockIdx.x;
    const int w   = tid >> 6;
    const int l   = tid & 63;
    const int l15 = l & 15;
    const int lk  = l >> 4;

    float* qs   = (float*)(smem + QS_OFF);
    float* b2s  = (float*)(smem + B2S_OFF);
    float* w3s  = (float*)(smem + W3S_OFF);
    float* c1s  = (float*)(smem + C1S_OFF);
    float* scw  = (float*)(smem + SCW_OFF);
    int*   mks  = (int*)(smem + MASK_OFF);
    float* comb = (float*)(smem + COMB_OFF);
    float* po   = (float*)(smem + PO_OFF);
    float* a1s  = (float*)(smem + A1S_OFF);
    float* a2s  = (float*)(smem + A2S_OFF);
    float* b3s  = (float*)(smem + B3S_OFF);

    // ---- phase 0: small stages + in-kernel c1 (waves 4-7) ----
    if (tid < 128) qs[tid] = query[bb * 128 + tid];
    else if (tid < 256) {
        int i = tid - 128;
        if (i < Hsz * 32) b2s[i] = b2[i];
    }
    if (tid >= 480 && tid < 492) {
        int i = tid - 480;
        if (i < 4) a1s[i] = a1[i];
        else if (i < 8) a2s[i - 4] = a2[i - 4];
        else b3s[i - 8] = b3[i - 8];
    }
    if (tid < SP)  mks[tid] = (tid < Ssz) ? kmask[bb * Ssz + tid] : 0;
    if (tid >= 256 && tid < 384) w3s[tid - 256] = W3[tid - 256];
    if (tid >= 256) {   // c1[n] = b1[n] + sum_j W1diffT[j][n]*q[j]
        int n = tid - 256;
        float acc0 = b1[n], acc1 = 0.f;
        #pragma unroll 4
        for (int j = 0; j < 128; j += 2) {
            acc0 += W1diffT[j * 256 + n] * query[bb * 128 + j];
            acc1 += W1diffT[(j + 1) * 256 + n] * query[bb * 128 + j + 1];
        }
        c1s[n] = acc0 + acc1;
    }
    __syncthreads();

    // wave roles
    const int wr = w & 1;    // M interleave within a pass
    const int wc = w >> 1;   // head (64 N-cols of layer-1)
    const int h2 = w >> 1;   // layer-2 head
    const int mtl = w & 1;   // layer-2 tile interleave
    const f32x4 fz = {0.f, 0.f, 0.f, 0.f};

    float c1v[4];
    #pragma unroll
    for (int nt = 0; nt < 4; ++nt) c1v[nt] = c1s[wc * 64 + nt * 16 + l15];
    const float a1v = a1s[wc];
    float b2v[2], w3v[2];
    #pragma unroll
    for (int nt = 0; nt < 2; ++nt) {
        b2v[nt] = b2s[h2 * 32 + nt * 16 + l15];
        w3v[nt] = w3s[h2 * 32 + nt * 16 + l15];
    }
    const float a2v = a2s[h2];
    const float b3v = b3s[h2];

    // ---- two passes: layer-1 (rows p*112..), H1C write, layer-2/3 ----
    #pragma unroll 1
    for (int p = 0; p < 2; ++p) {
        const int TT = (p == 0) ? 7 : 6;       // 16-row tiles in this pass
        f32x4 acc[4][4];
        #pragma unroll
        for (int i = 0; i < 4; ++i)
            #pragma unroll
            for (int n = 0; n < 4; ++n) acc[i][n] = fz;

        #pragma unroll 1
        for (int t = 0; t < 4; ++t) {
            const int k0 = 32 * t + 8 * lk;    // element offset in K=128
            float qv[8];
            #pragma unroll
            for (int j = 0; j < 8; ++j) qv[j] = qs[k0 + j];
            // B-fragments: W1eff = W1sum + W1c * q  (built in regs)
            short8 bfr[4];
            #pragma unroll
            for (int nt = 0; nt < 4; ++nt) {
                int n = wc * 64 + nt * 16 + l15;
                const float4* ps = (const float4*)(W1sum + n * 128 + k0);
                const float4* pc = (const float4*)(W1c + n * 128 + k0);
                float4 s0 = ps[0], s1 = ps[1];
                float4 c0 = pc[0], c1f = pc[1];
                bfr[nt][0] = (short)f2bf(s0.x + c0.x * qv[0]);
                bfr[nt][1] = (short)f2bf(s0.y + c0.y * qv[1]);
                bfr[nt][2] = (short)f2bf(s0.z + c0.z * qv[2]);
                bfr[nt][3] = (short)f2bf(s0.w + c0.w * qv[3]);
                bfr[nt][4] = (short)f2bf(s1.x + c1f.x * qv[4]);
                bfr[nt][5] = (short)f2bf(s1.y + c1f.y * qv[5]);
                bfr[nt][6] = (short)f2bf(s1.z + c1f.z * qv[6]);
                bfr[nt][7] = (short)f2bf(s1.w + c1f.w * qv[7]);
            }
            // A-fragments straight from global f32 keys
            #pragma unroll
            for (int i = 0; i < 4; ++i) {
                int lt = 2 * i + wr;
                if (lt < TT) {
                    int grow = p * 112 + lt * 16 + l15;
                    int rowc = (grow < Ssz) ? grow : (Ssz - 1);   // clamp; masked later
                    const float4* pk = (const float4*)(keys + (size_t)(bb * Ssz + rowc) * Dsz + k0);
                    float4 k0v = pk[0], k1v = pk[1];
                    short8 afr;
                    afr[0] = (short)f2bf(k0v.x); afr[1] = (short)f2bf(k0v.y);
                    afr[2] = (short)f2bf(k0v.z); afr[3] = (short)f2bf(k0v.w);
                    afr[4] = (short)f2bf(k1v.x); afr[5] = (short)f2bf(k1v.y);
                    afr[6] = (short)f2bf(k1v.z); afr[7] = (short)f2bf(k1v.w);
                    #pragma unroll
                    for (int nt = 0; nt < 4; ++nt)
                        acc[i][nt] = __builtin_amdgcn_mfma_f32_16x16x32_bf16(afr, bfr[nt], acc[i][nt], 0, 0, 0);
                }
            }
        }

        // leaky(h1)+c1 -> H1C (bf16, swizzled)
        #pragma unroll
        for (int i = 0; i < 4; ++i) {
            int lt = 2 * i + wr;
            if (lt < TT) {
                #pragma unroll
                for (int nt = 0; nt < 4; ++nt) {
                    int n = wc * 64 + nt * 16 + l15;
                    #pragma unroll
                    for (int r = 0; r < 4; ++r) {
                        float v = acc[i][nt][r] + c1v[nt];
                        v = (v >= 0.f) ? v : a1v * v;
                        int lrow = lt * 16 + lk * 4 + r;
                        int off = H1C_OFF + ((((lrow << 9) + (n << 1))) ^ ((lrow & 7) << 4));
                        *(ushort_t*)(smem + off) = f2bf(v);
                    }
                }
            }
        }
        __syncthreads();

        // layer 2+3 on this chunk; W2 B-fragments from L2-hot global
        short8 w2f[2][2];
        #pragma unroll
        for (int kt = 0; kt < 2; ++kt)
            #pragma unroll
            for (int nt = 0; nt < 2; ++nt) {
                int e = nt * 16 + l15;
                int kk = kt * 32 + lk * 8;
                w2f[kt][nt] = *(const short8*)(W2bf + h2 * 2048 + e * 64 + kk);
            }
        for (int t2 = mtl; t2 < TT; t2 += 2) {
            f32x4 acc2[2];
            acc2[0] = fz; acc2[1] = fz;
            #pragma unroll
            for (int kt = 0; kt < 2; ++kt) {
                int lrow = t2 * 16 + l15;
                int kk = kt * 32 + lk * 8;
                int aoff = H1C_OFF + ((((lrow << 9) + ((h2 * 64 + kk) << 1))) ^ ((lrow & 7) << 4));
                short8 afr = *(const short8*)(smem + aoff);
                #pragma unroll
                for (int nt = 0; nt < 2; ++nt)
                    acc2[nt] = __builtin_amdgcn_mfma_f32_16x16x32_bf16(afr, w2f[kt][nt], acc2[nt], 0, 0, 0);
            }
            #pragma unroll
            for (int r = 0; r < 4; ++r) {
                float sum = 0.f;
                #pragma unroll
                for (int nt = 0; nt < 2; ++nt) {
                    float v = acc2[nt][r] + b2v[nt];
                    v = (v >= 0.f) ? v : a2v * v;
                    sum += v * w3v[nt];
                }
                sum += __shfl_xor(sum, 1);
                sum += __shfl_xor(sum, 2);
                sum += __shfl_xor(sum, 4);
                sum += __shfl_xor(sum, 8);
                if (l15 == 0) {
                    int sg = p * 112 + t2 * 16 + lk * 4 + r;
                    float tw = __expf(0.1f * (float)(sg - (Ssz - 1)));
                    float sc = (sum + b3v) * tw;
                    scw[h2 * SP + sg] = mks[sg] ? sc : -1.0e9f;
                }
            }
        }
        __syncthreads();
    }

    // ---- softmax per head (waves 0..3): scores -> weights in scw ----
    if (w < 4) {
        float xv[4], ex[4];
        float mx = -3.0e38f;
        #pragma unroll
        for (int i = 0; i < 4; ++i) {
            int s = l + 64 * i;
            xv[i] = (s < Ssz) ? scw[w * SP + s] : -1.0e30f;
            mx = fmaxf(mx, xv[i]);
        }
        #pragma unroll
        for (int m = 1; m < 64; m <<= 1) mx = fmaxf(mx, __shfl_xor(mx, m));
        float sm = 0.f;
        #pragma unroll
        for (int i = 0; i < 4; ++i) {
            int s = l + 64 * i;
            ex[i] = (s < Ssz) ? __expf(xv[i] - mx) : 0.f;
            sm += ex[i];
        }
        #pragma unroll
        for (int m = 1; m < 64; m <<= 1) sm += __shfl_xor(sm, m);
        float inv = 1.0f / sm;
        #pragma unroll
        for (int i = 0; i < 4; ++i) {
            int s = l + 64 * i;
            if (s < SP) scw[w * SP + s] = ex[i] * inv;
        }
    }
    __syncthreads();

    // avg_weights output
    if (tid < Ssz) {
        float aw = 0.25f * (scw[tid] + scw[SP + tid] + scw[2 * SP + tid] + scw[3 * SP + tid]);
        out[Bsz * Dsz + bb * Ssz + tid] = aw;
    }

    // ---- PV thread-parallel: thread (h = tid>>7, d = tid&127) ----
    {
        int h = tid >> 7, d = tid & 127;
        const float* kb = keys + (size_t)bb * Ssz * Dsz + d;
        const float* wrow = scw + h * SP;
        float s0 = 0.f, s1 = 0.f, s2 = 0.f, s3 = 0.f;
        #pragma unroll 2
        for (int s = 0; s < Ssz; s += 4) {
            s0 += wrow[s]     * kb[(size_t)s * Dsz];
            s1 += wrow[s + 1] * kb[(size_t)(s + 1) * Dsz];
            s2 += wrow[s + 2] * kb[(size_t)(s + 2) * Dsz];
            s3 += wrow[s + 3] * kb[(size_t)(s + 3) * Dsz];
        }
        po[h * 128 + d] = 0.25f * ((s0 + s1) + (s2 + s3));
    }
    __syncthreads();

    // combined = mean over heads
    if (tid < Dsz) comb[tid] = po[tid] + po[128 + tid] + po[256 + tid] + po[384 + tid];
    __syncthreads();

    // ---- output projection, all 512 threads ----
    {
        int d = tid & 127, part = tid >> 7;
        float o = 0.f;
        const float* wp = WoT + (size_t)part * 32 * 128 + d;
        #pragma unroll 8
        for (int j = 0; j < 32; ++j) o += comb[part * 32 + j] * wp[j * 128];
        po[part * 128 + d] = o;
    }
    __syncthreads();
    if (tid < Dsz) {
        out[bb * Dsz + tid] = bo[tid] + po[tid] + po[128 + tid] + po[256 + tid] + po[384 + tid];
    }
}

// ws layout (bytes): W1sum 131072 | W1c 131072 | W1diffT 131072 | WoT 65536 | W2bf 16384
extern "C" void kernel_launch(void* const* d_in, const int* in_sizes, int n_in,
                              void* d_out, int out_size, void* d_ws, size_t ws_size,
                              hipStream_t stream) {
    const float* query = (const float*)d_in[0];
    const float* keys  = (const float*)d_in[1];
    const int*   kmask = (const int*)d_in[2];
    const float* W1    = (const float*)d_in[3];
    const float* b1    = (const float*)d_in[4];
    const float* a1    = (const float*)d_in[5];
    const float* W2    = (const float*)d_in[6];
    const float* b2    = (const float*)d_in[7];
    const float* a2    = (const float*)d_in[8];
    const float* W3    = (const float*)d_in[9];
    const float* b3    = (const float*)d_in[10];
    const float* Wo    = (const float*)d_in[11];
    const float* bo    = (const float*)d_in[12];
    float* out = (float*)d_out;

    char* ws = (char*)d_ws;
    float*    W1sum   = (float*)(ws);
    float*    W1c     = (float*)(ws + 131072);
    float*    W1diffT = (float*)(ws + 262144);
    float*    WoT     = (float*)(ws + 393216);
    ushort_t* W2bf    = (ushort_t*)(ws + 458752);

    hipFuncSetAttribute(reinterpret_cast<const void*>(attn_kernel),
                        hipFuncAttributeMaxDynamicSharedMemorySize, SMEM_BYTES);

    prep_kernel<<<128, 256, 0, stream>>>(W1, W2, Wo, W1sum, W1c, W1diffT, WoT, W2bf);
    attn_kernel<<<Bsz, 512, SMEM_BYTES, stream>>>(query, keys, kmask, a1, b2, a2, W3, b3, b1, bo,
                                                  W1sum, W1c, W1diffT, WoT, W2bf, out);
}

// Round 4
// 432.525 us; speedup vs baseline: 1.8358x; 1.8358x over previous
//
#include <hip/hip_runtime.h>
#include <hip/hip_bf16.h>
#include <stdint.h>

// Problem constants
#define Bsz 2048
#define Ssz 200
#define Dsz 128
#define SP  224   // padded S for score buffer

typedef __attribute__((ext_vector_type(8))) short short8;
typedef __attribute__((ext_vector_type(4))) float f32x4;
typedef unsigned short ushort_t;
typedef unsigned int uint_t;

// ---- LDS byte offsets (total 74,112 <= 80 KB -> 2 blocks/CU) ----
#define H1C0_OFF   0        // [64][256] bf16 swz   32,768
#define H1C1_OFF   32768    // [64][256] bf16 swz   32,768
#define SCW_OFF    65536    // [4][224] f32          3,584
#define C1S_OFF    69120    // [256] f32             1,024
#define QS_OFF     70144    // [128] f32               512
#define MKS_OFF    70656    // [224] int               896
#define COMB_OFF   71552    // [128] f32               512
#define PO_OFF     72064    // [4][128] f32          2,048
#define SMEM_BYTES 74112

__device__ __forceinline__ ushort_t f2bf(float x) {
    union { float f; uint_t u; } v; v.f = x;
    uint_t u = v.u;
    u += 0x7FFFu + ((u >> 16) & 1u);   // round-to-nearest-even
    return (ushort_t)(u >> 16);
}

// ---------- prep: fold W1, transpose Wo, cast W2 ----------
__global__ void prep_kernel(const float* __restrict__ W1, const float* __restrict__ W2,
                            const float* __restrict__ Wo,
                            float* __restrict__ W1sum, float* __restrict__ W1c,
                            float* __restrict__ W1diffT, float* __restrict__ WoT,
                            ushort_t* __restrict__ W2bf) {
    int i = blockIdx.x * blockDim.x + threadIdx.x;
    if (i < 32768) {                       // n in [0,256), j in [0,128)
        int n = i >> 7, j = i & 127;
        float a  = W1[n * 512 + j];        // keys part
        float dd = W1[n * 512 + 384 + j];  // (k - q) part
        W1sum[i] = a + dd;                 // coeff of k
        W1c[i]   = W1[n * 512 + 256 + j];  // coeff of k*q
        W1diffT[j * 256 + n] = W1[n * 512 + 128 + j] - dd;  // coeff of q (transposed)
    }
    if (i < 16384) {                       // WoT[j][d] = Wo[d][j]
        int j = i >> 7, d = i & 127;
        WoT[i] = Wo[d * 128 + j];
    }
    if (i < 8192) W2bf[i] = f2bf(W2[i]);   // flat [h][e][k], k fastest
}

// ---------- per-b bias: c1[b][n] = b1[n] + sum_j W1diffT[j][n]*q[b][j] ----------
__global__ void c1_kernel(const float* __restrict__ query, const float* __restrict__ W1diffT,
                          const float* __restrict__ b1, float* __restrict__ c1out) {
    __shared__ float qs[128];
    int b = blockIdx.x, t = threadIdx.x;
    if (t < 128) qs[t] = query[b * 128 + t];
    __syncthreads();
    float acc = b1[t];
    #pragma unroll 8
    for (int j = 0; j < 128; ++j) acc += W1diffT[j * 256 + t] * qs[j];
    c1out[b * 256 + t] = acc;
}

// ---------- per-b folded layer-1 weight, bf16: W1eff = W1sum + W1c * q ----------
__global__ void w1eff_kernel(const float* __restrict__ query, const float* __restrict__ W1sum,
                             const float* __restrict__ W1c, ushort_t* __restrict__ W1g) {
    __shared__ float qs[128];
    int b = blockIdx.x, t = threadIdx.x;
    if (t < 128) qs[t] = query[b * 128 + t];
    __syncthreads();
    #pragma unroll 4
    for (int it = 0; it < 16; ++it) {
        int c = t + 256 * it;              // [0, 4096): 8 elements each
        int e0 = c * 8;                    // flat element offset (= n*128 + k0)
        int k0 = e0 & 127;
        const float4* ps = (const float4*)(W1sum + e0);
        const float4* pc = (const float4*)(W1c + e0);
        float4 s0 = ps[0], s1 = ps[1];
        float4 c0 = pc[0], c1f = pc[1];
        const float4* pq = (const float4*)(qs + k0);
        float4 q0 = pq[0], q1 = pq[1];
        short8 o;
        o[0] = (short)f2bf(s0.x + c0.x * q0.x);
        o[1] = (short)f2bf(s0.y + c0.y * q0.y);
        o[2] = (short)f2bf(s0.z + c0.z * q0.z);
        o[3] = (short)f2bf(s0.w + c0.w * q0.w);
        o[4] = (short)f2bf(s1.x + c1f.x * q1.x);
        o[5] = (short)f2bf(s1.y + c1f.y * q1.y);
        o[6] = (short)f2bf(s1.z + c1f.z * q1.z);
        o[7] = (short)f2bf(s1.w + c1f.w * q1.w);
        *(short8*)(W1g + (size_t)b * 32768 + e0) = o;
    }
}

// ---------- fused main kernel: one block per batch element, 2 blocks/CU ----------
template <int USE_W1G>
__launch_bounds__(512, 4)
__global__ void attn_kernel(const float* __restrict__ query, const float* __restrict__ keys,
                            const int* __restrict__ kmask,
                            const float* __restrict__ a1, const float* __restrict__ b2,
                            const float* __restrict__ a2, const float* __restrict__ W3,
                            const float* __restrict__ b3, const float* __restrict__ bo,
                            const float* __restrict__ W1sum, const float* __restrict__ W1c,
                            const float* __restrict__ WoT, const ushort_t* __restrict__ W2bf,
                            const float* __restrict__ c1ws, const ushort_t* __restrict__ W1g,
                            float* __restrict__ out) {
    extern __shared__ char smem[];
    const int tid = threadIdx.x;
    const int bb  = blockIdx.x;
    const int w   = tid >> 6;
    const int l   = tid & 63;
    const int l15 = l & 15;
    const int lk  = l >> 4;

    float* qs   = (float*)(smem + QS_OFF);
    float* c1s  = (float*)(smem + C1S_OFF);
    float* scw  = (float*)(smem + SCW_OFF);
    int*   mks  = (int*)(smem + MKS_OFF);
    float* comb = (float*)(smem + COMB_OFF);
    float* po   = (float*)(smem + PO_OFF);

    // ---- phase 0: small stages ----
    if (!USE_W1G) { if (tid < 128) qs[tid] = query[bb * 128 + tid]; }
    if (tid < SP) mks[tid] = (tid < Ssz) ? kmask[bb * Ssz + tid] : 0;
    if (tid >= 256) c1s[tid - 256] = c1ws[bb * 256 + (tid - 256)];
    __syncthreads();

    // wave roles
    const int wr = w & 1;    // layer-1 M interleave
    const int wc = w >> 1;   // layer-1 head (64 N-cols); also layer-2 head
    const int h2 = w >> 1;
    const int mtl = w & 1;   // layer-2 tile interleave
    const f32x4 fz = {0.f, 0.f, 0.f, 0.f};

    float c1v[4];
    #pragma unroll
    for (int nt = 0; nt < 4; ++nt) c1v[nt] = c1s[wc * 64 + nt * 16 + l15];
    const float a1v = a1[wc];
    float b2v[2], w3v[2];
    #pragma unroll
    for (int nt = 0; nt < 2; ++nt) {
        b2v[nt] = b2[h2 * 32 + nt * 16 + l15];
        w3v[nt] = W3[h2 * 32 + nt * 16 + l15];
    }
    const float a2v = a2[h2];
    const float b3v = b3[h2];
    short8 w2f[2][2];
    #pragma unroll
    for (int kt = 0; kt < 2; ++kt)
        #pragma unroll
        for (int nt = 0; nt < 2; ++nt)
            w2f[kt][nt] = *(const short8*)(W2bf + h2 * 2048 + (nt * 16 + l15) * 64 + kt * 32 + lk * 8);

    // ---- 4 passes over M (4 tiles of 16 rows each; tile 12 in pass 3) ----
    #pragma unroll 1
    for (int p = 0; p < 4; ++p) {
        f32x4 acc[2][4];
        #pragma unroll
        for (int i = 0; i < 2; ++i)
            #pragma unroll
            for (int n = 0; n < 4; ++n) acc[i][n] = fz;

        #pragma unroll 1
        for (int t = 0; t < 4; ++t) {
            const int k0 = 32 * t + 8 * lk;
            short8 bfr[4];
            if (USE_W1G) {
                #pragma unroll
                for (int nt = 0; nt < 4; ++nt) {
                    int n = wc * 64 + nt * 16 + l15;
                    bfr[nt] = *(const short8*)(W1g + (size_t)bb * 32768 + n * 128 + k0);
                }
            } else {
                const float4* pq = (const float4*)(qs + k0);
                float4 q0 = pq[0], q1 = pq[1];
                #pragma unroll
                for (int nt = 0; nt < 4; ++nt) {
                    int n = wc * 64 + nt * 16 + l15;
                    const float4* ps = (const float4*)(W1sum + n * 128 + k0);
                    const float4* pc = (const float4*)(W1c + n * 128 + k0);
                    float4 s0 = ps[0], s1 = ps[1];
                    float4 c0 = pc[0], c1f = pc[1];
                    bfr[nt][0] = (short)f2bf(s0.x + c0.x * q0.x);
                    bfr[nt][1] = (short)f2bf(s0.y + c0.y * q0.y);
                    bfr[nt][2] = (short)f2bf(s0.z + c0.z * q0.z);
                    bfr[nt][3] = (short)f2bf(s0.w + c0.w * q0.w);
                    bfr[nt][4] = (short)f2bf(s1.x + c1f.x * q1.x);
                    bfr[nt][5] = (short)f2bf(s1.y + c1f.y * q1.y);
                    bfr[nt][6] = (short)f2bf(s1.z + c1f.z * q1.z);
                    bfr[nt][7] = (short)f2bf(s1.w + c1f.w * q1.w);
                }
            }
            #pragma unroll
            for (int i = 0; i < 2; ++i) {
                int gmt = 4 * p + 2 * i + wr;
                if (gmt < 13) {
                    int grow = gmt * 16 + l15;
                    int rowc = (grow < Ssz) ? grow : (Ssz - 1);   // clamp; masked later
                    const float4* pk = (const float4*)(keys + (size_t)(bb * Ssz + rowc) * Dsz + k0);
                    float4 k0v = pk[0], k1v = pk[1];
                    short8 afr;
                    afr[0] = (short)f2bf(k0v.x); afr[1] = (short)f2bf(k0v.y);
                    afr[2] = (short)f2bf(k0v.z); afr[3] = (short)f2bf(k0v.w);
                    afr[4] = (short)f2bf(k1v.x); afr[5] = (short)f2bf(k1v.y);
                    afr[6] = (short)f2bf(k1v.z); afr[7] = (short)f2bf(k1v.w);
                    #pragma unroll
                    for (int nt = 0; nt < 4; ++nt)
                        acc[i][nt] = __builtin_amdgcn_mfma_f32_16x16x32_bf16(afr, bfr[nt], acc[i][nt], 0, 0, 0);
                }
            }
        }

        // leaky(h1)+c1 -> H1C buffer (p&1), bf16 swizzled; local rows [0,64)
        char* h1buf = smem + ((p & 1) ? H1C1_OFF : H1C0_OFF);
        #pragma unroll
        for (int i = 0; i < 2; ++i) {
            int lt = 2 * i + wr;
            int gmt = 4 * p + lt;
            if (gmt < 13) {
                #pragma unroll
                for (int nt = 0; nt < 4; ++nt) {
                    int n = wc * 64 + nt * 16 + l15;
                    #pragma unroll
                    for (int r = 0; r < 4; ++r) {
                        float v = acc[i][nt][r] + c1v[nt];
                        v = (v >= 0.f) ? v : a1v * v;
                        int lrow = lt * 16 + lk * 4 + r;
                        int off = ((lrow << 9) + (n << 1)) ^ ((lrow & 7) << 4);
                        *(ushort_t*)(h1buf + off) = f2bf(v);
                    }
                }
            }
        }
        __syncthreads();

        // layer 2+3 on this pass's 64 rows
        for (int t2 = mtl; t2 < 4; t2 += 2) {
            if (4 * p + t2 < 13) {
                f32x4 acc2[2];
                acc2[0] = fz; acc2[1] = fz;
                #pragma unroll
                for (int kt = 0; kt < 2; ++kt) {
                    int lrow = t2 * 16 + l15;
                    int kk = kt * 32 + lk * 8;
                    int aoff = ((lrow << 9) + ((h2 * 64 + kk) << 1)) ^ ((lrow & 7) << 4);
                    short8 afr = *(const short8*)(h1buf + aoff);
                    #pragma unroll
                    for (int nt = 0; nt < 2; ++nt)
                        acc2[nt] = __builtin_amdgcn_mfma_f32_16x16x32_bf16(afr, w2f[kt][nt], acc2[nt], 0, 0, 0);
                }
                #pragma unroll
                for (int r = 0; r < 4; ++r) {
                    float sum = 0.f;
                    #pragma unroll
                    for (int nt = 0; nt < 2; ++nt) {
                        float v = acc2[nt][r] + b2v[nt];
                        v = (v >= 0.f) ? v : a2v * v;
                        sum += v * w3v[nt];
                    }
                    sum += __shfl_xor(sum, 1);
                    sum += __shfl_xor(sum, 2);
                    sum += __shfl_xor(sum, 4);
                    sum += __shfl_xor(sum, 8);
                    if (l15 == 0) {
                        int sg = p * 64 + t2 * 16 + lk * 4 + r;
                        float tw = __expf(0.1f * (float)(sg - (Ssz - 1)));
                        float sc = (sum + b3v) * tw;
                        scw[h2 * SP + sg] = mks[sg] ? sc : -1.0e9f;
                    }
                }
            }
        }
        // no trailing barrier: next pass writes the other H1C buffer; the
        // per-pass barrier above orders reuse two passes out.
    }
    __syncthreads();

    // ---- softmax per head (waves 0..3): scores -> weights in scw ----
    if (w < 4) {
        float xv[4], ex[4];
        float mx = -3.0e38f;
        #pragma unroll
        for (int i = 0; i < 4; ++i) {
            int s = l + 64 * i;
            xv[i] = (s < Ssz) ? scw[w * SP + s] : -1.0e30f;
            mx = fmaxf(mx, xv[i]);
        }
        #pragma unroll
        for (int m = 1; m < 64; m <<= 1) mx = fmaxf(mx, __shfl_xor(mx, m));
        float sm = 0.f;
        #pragma unroll
        for (int i = 0; i < 4; ++i) {
            int s = l + 64 * i;
            ex[i] = (s < Ssz) ? __expf(xv[i] - mx) : 0.f;
            sm += ex[i];
        }
        #pragma unroll
        for (int m = 1; m < 64; m <<= 1) sm += __shfl_xor(sm, m);
        float inv = 1.0f / sm;
        #pragma unroll
        for (int i = 0; i < 4; ++i) {
            int s = l + 64 * i;
            if (s < SP) scw[w * SP + s] = ex[i] * inv;
        }
    }
    __syncthreads();

    // avg_weights output
    if (tid < Ssz) {
        float aw = 0.25f * (scw[tid] + scw[SP + tid] + scw[2 * SP + tid] + scw[3 * SP + tid]);
        out[Bsz * Dsz + bb * Ssz + tid] = aw;
    }

    // ---- PV thread-parallel: thread (h = tid>>7, d = tid&127) ----
    {
        int h = tid >> 7, d = tid & 127;
        const float* kb = keys + (size_t)bb * Ssz * Dsz + d;
        const float* wrow = scw + h * SP;
        float s0 = 0.f, s1 = 0.f, s2 = 0.f, s3 = 0.f;
        #pragma unroll 2
        for (int s = 0; s < Ssz; s += 4) {
            s0 += wrow[s]     * kb[(size_t)s * Dsz];
            s1 += wrow[s + 1] * kb[(size_t)(s + 1) * Dsz];
            s2 += wrow[s + 2] * kb[(size_t)(s + 2) * Dsz];
            s3 += wrow[s + 3] * kb[(size_t)(s + 3) * Dsz];
        }
        po[h * 128 + d] = 0.25f * ((s0 + s1) + (s2 + s3));
    }
    __syncthreads();

    // combined = mean over heads
    if (tid < Dsz) comb[tid] = po[tid] + po[128 + tid] + po[256 + tid] + po[384 + tid];
    __syncthreads();

    // ---- output projection, all 512 threads ----
    {
        int d = tid & 127, part = tid >> 7;
        float o = 0.f;
        const float* wp = WoT + (size_t)part * 32 * 128 + d;
        #pragma unroll 8
        for (int j = 0; j < 32; ++j) o += comb[part * 32 + j] * wp[j * 128];
        po[part * 128 + d] = o;
    }
    __syncthreads();
    if (tid < Dsz) {
        out[bb * Dsz + tid] = bo[tid] + po[tid] + po[128 + tid] + po[256 + tid] + po[384 + tid];
    }
}

// ws layout (bytes): W1sum 131072 | W1c 131072 | W1diffT 131072 | WoT 65536 |
//                    W2bf 16384 | c1 2097152 | W1effbf 134217728  => 136,790,016 total
extern "C" void kernel_launch(void* const* d_in, const int* in_sizes, int n_in,
                              void* d_out, int out_size, void* d_ws, size_t ws_size,
                              hipStream_t stream) {
    const float* query = (const float*)d_in[0];
    const float* keys  = (const float*)d_in[1];
    const int*   kmask = (const int*)d_in[2];
    const float* W1    = (const float*)d_in[3];
    const float* b1    = (const float*)d_in[4];
    const float* a1    = (const float*)d_in[5];
    const float* W2    = (const float*)d_in[6];
    const float* b2    = (const float*)d_in[7];
    const float* a2    = (const float*)d_in[8];
    const float* W3    = (const float*)d_in[9];
    const float* b3    = (const float*)d_in[10];
    const float* Wo    = (const float*)d_in[11];
    const float* bo    = (const float*)d_in[12];
    float* out = (float*)d_out;

    char* ws = (char*)d_ws;
    float*    W1sum   = (float*)(ws);
    float*    W1c     = (float*)(ws + 131072);
    float*    W1diffT = (float*)(ws + 262144);
    float*    WoT     = (float*)(ws + 393216);
    ushort_t* W2bf    = (ushort_t*)(ws + 458752);
    float*    c1ws    = (float*)(ws + 475136);
    ushort_t* W1g     = (ushort_t*)(ws + 2572288);

    const bool useW1G = ws_size >= (size_t)2572288 + (size_t)Bsz * 32768 * 2;

    prep_kernel<<<128, 256, 0, stream>>>(W1, W2, Wo, W1sum, W1c, W1diffT, WoT, W2bf);
    c1_kernel<<<Bsz, 256, 0, stream>>>(query, W1diffT, b1, c1ws);

    if (useW1G) {
        hipFuncSetAttribute(reinterpret_cast<const void*>(&attn_kernel<1>),
                            hipFuncAttributeMaxDynamicSharedMemorySize, SMEM_BYTES);
        w1eff_kernel<<<Bsz, 256, 0, stream>>>(query, W1sum, W1c, W1g);
        attn_kernel<1><<<Bsz, 512, SMEM_BYTES, stream>>>(query, keys, kmask, a1, b2, a2, W3, b3,
                                                         bo, W1sum, W1c, WoT, W2bf, c1ws, W1g, out);
    } else {
        hipFuncSetAttribute(reinterpret_cast<const void*>(&attn_kernel<0>),
                            hipFuncAttributeMaxDynamicSharedMemorySize, SMEM_BYTES);
        attn_kernel<0><<<Bsz, 512, SMEM_BYTES, stream>>>(query, keys, kmask, a1, b2, a2, W3, b3,
                                                         bo, W1sum, W1c, WoT, W2bf, c1ws, W1g, out);
    }
}

// Round 5
// 391.756 us; speedup vs baseline: 2.0268x; 1.1041x over previous
//
#include <hip/hip_runtime.h>
#include <hip/hip_bf16.h>
#include <stdint.h>

// Problem constants
#define Bsz 2048
#define Ssz 200
#define Dsz 128
#define SP  224

typedef __attribute__((ext_vector_type(8))) short short8;
typedef __attribute__((ext_vector_type(4))) float f32x4;
typedef unsigned short ushort_t;
typedef unsigned int uint_t;

#define LGKM_FENCE() asm volatile("s_waitcnt lgkmcnt(0)" ::: "memory")

__device__ __forceinline__ ushort_t cvtbf(float x) {
    __hip_bfloat16 h = __float2bfloat16(x);   // RTNE; compiler can pair into v_cvt_pk_bf16_f32
    ushort_t u;
    __builtin_memcpy(&u, &h, 2);
    return u;
}

// ---------- prep: fold W1, transpose Wo, cast W2 ----------
__global__ void prep_kernel(const float* __restrict__ W1, const float* __restrict__ W2,
                            const float* __restrict__ Wo,
                            float* __restrict__ W1sum, float* __restrict__ W1c,
                            float* __restrict__ W1diffT, float* __restrict__ WoT,
                            ushort_t* __restrict__ W2bf) {
    int i = blockIdx.x * blockDim.x + threadIdx.x;
    if (i < 32768) {                       // n in [0,256), j in [0,128)
        int n = i >> 7, j = i & 127;
        float a  = W1[n * 512 + j];        // keys part
        float dd = W1[n * 512 + 384 + j];  // (k - q) part
        W1sum[i] = a + dd;                 // coeff of k
        W1c[i]   = W1[n * 512 + 256 + j];  // coeff of k*q
        W1diffT[j * 256 + n] = W1[n * 512 + 128 + j] - dd;  // coeff of q (transposed)
    }
    if (i < 16384) {                       // WoT[j][d] = Wo[d][j]
        int j = i >> 7, d = i & 127;
        WoT[i] = Wo[d * 128 + j];
    }
    if (i < 8192) W2bf[i] = cvtbf(W2[i]); // flat [h][e][k], k fastest
}

// ---------- per-b: c1 bias + folded layer-1 weight in MFMA-fragment order ----------
// W1g2[b] layout: slot o in [0,4096): t4=o>>10, lk=(o>>8)&3, n=o&255
//   holds bf16x8 of W1eff[n][t4*32+lk*8 .. +8]; W1eff = W1sum + W1c*q[b]
__global__ void w1effc1_kernel(const float* __restrict__ query, const float* __restrict__ W1sum,
                               const float* __restrict__ W1c, const float* __restrict__ W1diffT,
                               const float* __restrict__ b1,
                               ushort_t* __restrict__ W1g2, float* __restrict__ c1out) {
    __shared__ float qs[128];
    int b = blockIdx.x, t = threadIdx.x;
    if (t < 128) qs[t] = query[b * 128 + t];
    __syncthreads();
    // c1[n] = b1[n] + sum_j W1diffT[j][n]*q[j]
    {
        float acc = b1[t];
        #pragma unroll 8
        for (int j = 0; j < 128; ++j) acc += W1diffT[j * 256 + t] * qs[j];
        c1out[b * 256 + t] = acc;
    }
    // fold: out-slot-major so writes are fully coalesced
    ushort_t* wout = W1g2 + ((size_t)b << 15);
    #pragma unroll 2
    for (int it = 0; it < 16; ++it) {
        int o  = t + 256 * it;
        int t4 = o >> 10, lk = (o >> 8) & 3, n = o & 255;
        int k0 = t4 * 32 + lk * 8;
        const float4* ps = (const float4*)(W1sum + n * 128 + k0);
        const float4* pc = (const float4*)(W1c + n * 128 + k0);
        const float4* pq = (const float4*)(qs + k0);
        float4 s0 = ps[0], s1 = ps[1];
        float4 c0 = pc[0], c1f = pc[1];
        float4 q0 = pq[0], q1 = pq[1];
        short8 ov;
        ov[0] = (short)cvtbf(s0.x + c0.x * q0.x);
        ov[1] = (short)cvtbf(s0.y + c0.y * q0.y);
        ov[2] = (short)cvtbf(s0.z + c0.z * q0.z);
        ov[3] = (short)cvtbf(s0.w + c0.w * q0.w);
        ov[4] = (short)cvtbf(s1.x + c1f.x * q1.x);
        ov[5] = (short)cvtbf(s1.y + c1f.y * q1.y);
        ov[6] = (short)cvtbf(s1.z + c1f.z * q1.z);
        ov[7] = (short)cvtbf(s1.w + c1f.w * q1.w);
        *(short8*)(wout + (size_t)o * 8) = ov;
    }
}

// ---------- fused main kernel: 256 threads, wave = head, near-zero barriers ----------
__launch_bounds__(256, 3)
__global__ void attn_kernel(const float* __restrict__ keys, const int* __restrict__ kmask,
                            const float* __restrict__ a1, const float* __restrict__ b2,
                            const float* __restrict__ a2, const float* __restrict__ W3,
                            const float* __restrict__ b3, const float* __restrict__ bo,
                            const float* __restrict__ WoT, const ushort_t* __restrict__ W2bf,
                            const float* __restrict__ c1ws, const ushort_t* __restrict__ W1g2,
                            float* __restrict__ out) {
    __shared__ ushort_t h1s[4][2048];   // per-wave [32 rows][64 cols] bf16, XOR-swizzled
    __shared__ float scw[4][SP];        // per-head scores -> weights
    __shared__ float po[4][128];        // per-head PV output
    __shared__ float comb[128];
    __shared__ float po2[2][128];

    const int tid = threadIdx.x;
    const int bb  = blockIdx.x;
    const int w   = tid >> 6;           // wave == head
    const int l   = tid & 63;
    const int l15 = l & 15;
    const int lk  = l >> 4;

    // per-wave constants (all L2/L3-hot broadcast reads)
    float c1v[4];
    #pragma unroll
    for (int nt = 0; nt < 4; ++nt) c1v[nt] = c1ws[bb * 256 + w * 64 + nt * 16 + l15];
    const float a1v = a1[w];
    const float a2v = a2[w];
    const float b3v = b3[w];
    float b2v[2], w3v[2];
    #pragma unroll
    for (int nt = 0; nt < 2; ++nt) {
        b2v[nt] = b2[w * 32 + nt * 16 + l15];
        w3v[nt] = W3[w * 32 + nt * 16 + l15];
    }
    short8 w2f[2][2];
    #pragma unroll
    for (int kt = 0; kt < 2; ++kt)
        #pragma unroll
        for (int nt = 0; nt < 2; ++nt)
            w2f[kt][nt] = *(const short8*)(W2bf + w * 2048 + (nt * 16 + l15) * 64 + kt * 32 + lk * 8);

    const ushort_t* w1p = W1g2 + ((size_t)bb << 15);
    const float*    kb  = keys + (size_t)bb * Ssz * Dsz;
    char* h1b = (char*)&h1s[w][0];
    const f32x4 fz = {0.f, 0.f, 0.f, 0.f};

    // ---- 7 chunks of 2 M-tiles (13 tiles total); all wave-local, no barriers ----
    #pragma unroll 1
    for (int c = 0; c < 7; ++c) {
        const int TT = (c == 6) ? 1 : 2;
        f32x4 acc[2][4];
        #pragma unroll
        for (int i = 0; i < 2; ++i)
            #pragma unroll
            for (int n = 0; n < 4; ++n) acc[i][n] = fz;

        #pragma unroll 1
        for (int t = 0; t < 4; ++t) {
            const int k0 = t * 32 + lk * 8;
            short8 bfr[4];
            #pragma unroll
            for (int nt = 0; nt < 4; ++nt)
                bfr[nt] = *(const short8*)(w1p + ((size_t)((t * 4 + lk) * 256 + w * 64 + nt * 16 + l15)) * 8);
            #pragma unroll
            for (int i = 0; i < 2; ++i) {
                if (i < TT) {
                    int grow = (c * 2 + i) * 16 + l15;
                    int rowc = (grow < Ssz) ? grow : (Ssz - 1);   // clamp; masked later
                    const float4* pk = (const float4*)(kb + (size_t)rowc * Dsz + k0);
                    float4 a0 = pk[0], a1f = pk[1];
                    short8 afr;
                    afr[0] = (short)cvtbf(a0.x);  afr[1] = (short)cvtbf(a0.y);
                    afr[2] = (short)cvtbf(a0.z);  afr[3] = (short)cvtbf(a0.w);
                    afr[4] = (short)cvtbf(a1f.x); afr[5] = (short)cvtbf(a1f.y);
                    afr[6] = (short)cvtbf(a1f.z); afr[7] = (short)cvtbf(a1f.w);
                    #pragma unroll
                    for (int nt = 0; nt < 4; ++nt)
                        acc[i][nt] = __builtin_amdgcn_mfma_f32_16x16x32_bf16(afr, bfr[nt], acc[i][nt], 0, 0, 0);
                }
            }
        }

        // leaky(h1)+c1 -> wave-private scratch (bf16, XOR-swizzled rows)
        #pragma unroll
        for (int i = 0; i < 2; ++i) {
            if (i < TT) {
                #pragma unroll
                for (int nt = 0; nt < 4; ++nt) {
                    #pragma unroll
                    for (int r = 0; r < 4; ++r) {
                        float v = acc[i][nt][r] + c1v[nt];
                        v = (v >= 0.f) ? v : a1v * v;
                        int lr = i * 16 + lk * 4 + r;
                        int colb = (nt * 16 + l15) * 2;
                        *(ushort_t*)(h1b + lr * 128 + (colb ^ ((lr & 7) << 4))) = cvtbf(v);
                    }
                }
            }
        }
        LGKM_FENCE();   // wave-private RAW: writes drained before reads

        // layer 2+3 on this chunk's rows (wave-local)
        #pragma unroll
        for (int t2 = 0; t2 < 2; ++t2) {
            if (t2 < TT) {
                f32x4 acc2[2];
                acc2[0] = fz; acc2[1] = fz;
                #pragma unroll
                for (int kt = 0; kt < 2; ++kt) {
                    int lr = t2 * 16 + l15;
                    short8 afr = *(const short8*)(h1b + lr * 128 + ((kt * 64 + lk * 16) ^ ((lr & 7) << 4)));
                    #pragma unroll
                    for (int nt = 0; nt < 2; ++nt)
                        acc2[nt] = __builtin_amdgcn_mfma_f32_16x16x32_bf16(afr, w2f[kt][nt], acc2[nt], 0, 0, 0);
                }
                #pragma unroll
                for (int r = 0; r < 4; ++r) {
                    float sum = 0.f;
                    #pragma unroll
                    for (int nt = 0; nt < 2; ++nt) {
                        float v = acc2[nt][r] + b2v[nt];
                        v = (v >= 0.f) ? v : a2v * v;
                        sum += v * w3v[nt];
                    }
                    sum += __shfl_xor(sum, 1);
                    sum += __shfl_xor(sum, 2);
                    sum += __shfl_xor(sum, 4);
                    sum += __shfl_xor(sum, 8);
                    if (l15 == 0) {
                        int sg = (c * 2 + t2) * 16 + lk * 4 + r;
                        if (sg < Ssz) {
                            float tw = __expf(0.1f * (float)(sg - (Ssz - 1)));
                            float sc = (sum + b3v) * tw;
                            scw[w][sg] = kmask[bb * Ssz + sg] ? sc : -1.0e9f;
                        }
                    }
                }
            }
        }
        LGKM_FENCE();   // reads done before next chunk overwrites scratch
    }

    // ---- softmax, wave-local over this wave's head ----
    {
        float xv[4], ex[4];
        float mx = -3.0e38f;
        #pragma unroll
        for (int i = 0; i < 4; ++i) {
            int s = l + 64 * i;
            xv[i] = (s < Ssz) ? scw[w][s] : -1.0e30f;
            mx = fmaxf(mx, xv[i]);
        }
        #pragma unroll
        for (int m = 1; m < 64; m <<= 1) mx = fmaxf(mx, __shfl_xor(mx, m));
        float sm = 0.f;
        #pragma unroll
        for (int i = 0; i < 4; ++i) {
            int s = l + 64 * i;
            ex[i] = (s < Ssz) ? __expf(xv[i] - mx) : 0.f;
            sm += ex[i];
        }
        #pragma unroll
        for (int m = 1; m < 64; m <<= 1) sm += __shfl_xor(sm, m);
        float inv = 1.0f / sm;
        #pragma unroll
        for (int i = 0; i < 4; ++i) {
            int s = l + 64 * i;
            if (s < Ssz) scw[w][s] = ex[i] * inv;
        }
    }
    __syncthreads();   // barrier 1: all heads' weights visible

    // avg_weights output
    if (tid < Ssz) {
        float aw = 0.25f * (scw[0][tid] + scw[1][tid] + scw[2][tid] + scw[3][tid]);
        out[Bsz * Dsz + bb * Ssz + tid] = aw;
    }

    // ---- PV: wave w = head w; lane l covers d = 2l, 2l+1 (float2 coalesced) ----
    {
        const float2* kb2 = (const float2*)kb;
        float s0 = 0.f, s1 = 0.f;
        #pragma unroll 4
        for (int s = 0; s < Ssz; ++s) {
            float wv = scw[w][s];
            float2 kv = kb2[(size_t)s * 64 + l];
            s0 += wv * kv.x;
            s1 += wv * kv.y;
        }
        po[w][2 * l]     = s0;
        po[w][2 * l + 1] = s1;
    }
    __syncthreads();   // barrier 2

    if (tid < 128) comb[tid] = 0.25f * (po[0][tid] + po[1][tid] + po[2][tid] + po[3][tid]);
    __syncthreads();   // barrier 3

    // ---- output projection: 256 threads, 2 parts of 64 j each ----
    {
        int d = tid & 127, part = tid >> 7;
        float o = 0.f;
        const float* wp = WoT + (size_t)part * 64 * 128 + d;
        #pragma unroll 8
        for (int j = 0; j < 64; ++j) o += comb[part * 64 + j] * wp[j * 128];
        po2[part][d] = o;
    }
    __syncthreads();
    if (tid < 128) out[bb * Dsz + tid] = bo[tid] + po2[0][tid] + po2[1][tid];
}

// ws layout (bytes): W1sum 131072 | W1c 131072 | W1diffT 131072 | WoT 65536 |
//                    W2bf 16384 | c1 2097152 | W1g2 134217728  => 136,790,016 total
extern "C" void kernel_launch(void* const* d_in, const int* in_sizes, int n_in,
                              void* d_out, int out_size, void* d_ws, size_t ws_size,
                              hipStream_t stream) {
    const float* query = (const float*)d_in[0];
    const float* keys  = (const float*)d_in[1];
    const int*   kmask = (const int*)d_in[2];
    const float* W1    = (const float*)d_in[3];
    const float* b1    = (const float*)d_in[4];
    const float* a1    = (const float*)d_in[5];
    const float* W2    = (const float*)d_in[6];
    const float* b2    = (const float*)d_in[7];
    const float* a2    = (const float*)d_in[8];
    const float* W3    = (const float*)d_in[9];
    const float* b3    = (const float*)d_in[10];
    const float* Wo    = (const float*)d_in[11];
    const float* bo    = (const float*)d_in[12];
    float* out = (float*)d_out;

    char* ws = (char*)d_ws;
    float*    W1sum   = (float*)(ws);
    float*    W1c     = (float*)(ws + 131072);
    float*    W1diffT = (float*)(ws + 262144);
    float*    WoT     = (float*)(ws + 393216);
    ushort_t* W2bf    = (ushort_t*)(ws + 458752);
    float*    c1ws    = (float*)(ws + 475136);
    ushort_t* W1g2    = (ushort_t*)(ws + 2572288);

    prep_kernel<<<128, 256, 0, stream>>>(W1, W2, Wo, W1sum, W1c, W1diffT, WoT, W2bf);
    w1effc1_kernel<<<Bsz, 256, 0, stream>>>(query, W1sum, W1c, W1diffT, b1, W1g2, c1ws);
    attn_kernel<<<Bsz, 256, 0, stream>>>(keys, kmask, a1, b2, a2, W3, b3, bo,
                                         WoT, W2bf, c1ws, W1g2, out);
}

// Round 6
// 228.976 us; speedup vs baseline: 3.4677x; 1.7109x over previous
//
#include <hip/hip_runtime.h>
#include <hip/hip_bf16.h>
#include <stdint.h>

// Problem constants
#define Bsz 2048
#define Ssz 200
#define Dsz 128
#define SP  224

typedef __attribute__((ext_vector_type(8))) short short8;
typedef __attribute__((ext_vector_type(4))) float f32x4;
typedef unsigned short ushort_t;
typedef unsigned int uint_t;

#define LGKM_FENCE() do { asm volatile("s_waitcnt lgkmcnt(0)" ::: "memory"); \
                          __builtin_amdgcn_sched_barrier(0); } while (0)

// ---- LDS byte offsets (total 78,336 -> 2 blocks/CU) ----
#define KEYS_OFF   0        // [224][128] bf16, XOR-swizzled  57,344
#define H1S_OFF    57344    // [4][32][64] bf16 per-wave      16,384
#define SCW_OFF    73728    // [4][224] f32                    3,584
#define C1S_OFF    77312    // [256] f32                       1,024
#define SMEM_BYTES 78336
// aliases into H1S after the chunk loop (h1 scratch dead):
#define PO_OFF     57344    // [4][128] f32   2,048
#define COMB_OFF   59392    // [128] f32        512
#define PO2_OFF    59904    // [2][128] f32   1,024

__device__ __forceinline__ ushort_t cvtbf(float x) {
    union { float f; uint_t u; } v; v.f = x;
    uint_t u = v.u;
    u += 0x7FFFu + ((u >> 16) & 1u);   // RTNE
    return (ushort_t)(u >> 16);
}
__device__ __forceinline__ float bflo(uint_t kv) {
    union { uint_t u; float f; } v; v.u = kv << 16; return v.f;
}
__device__ __forceinline__ float bfhi(uint_t kv) {
    union { uint_t u; float f; } v; v.u = kv & 0xFFFF0000u; return v.f;
}

// ---------- prep: fold W1, transpose Wo, cast W2 ----------
__global__ void prep_kernel(const float* __restrict__ W1, const float* __restrict__ W2,
                            const float* __restrict__ Wo,
                            float* __restrict__ W1sum, float* __restrict__ W1c,
                            float* __restrict__ W1diffT, float* __restrict__ WoT,
                            ushort_t* __restrict__ W2bf) {
    int i = blockIdx.x * blockDim.x + threadIdx.x;
    if (i < 32768) {                       // n in [0,256), j in [0,128)
        int n = i >> 7, j = i & 127;
        float a  = W1[n * 512 + j];        // keys part
        float dd = W1[n * 512 + 384 + j];  // (k - q) part
        W1sum[i] = a + dd;                 // coeff of k
        W1c[i]   = W1[n * 512 + 256 + j];  // coeff of k*q
        W1diffT[j * 256 + n] = W1[n * 512 + 128 + j] - dd;  // coeff of q (transposed)
    }
    if (i < 16384) {                       // WoT[j][d] = Wo[d][j]
        int j = i >> 7, d = i & 127;
        WoT[i] = Wo[d * 128 + j];
    }
    if (i < 8192) W2bf[i] = cvtbf(W2[i]); // flat [h][e][k], k fastest
}

// ---------- fused main kernel: 256 threads, wave = head ----------
__launch_bounds__(256, 2)
__global__ void attn_kernel(const float* __restrict__ query, const float* __restrict__ keys,
                            const int* __restrict__ kmask,
                            const float* __restrict__ a1, const float* __restrict__ b2,
                            const float* __restrict__ a2, const float* __restrict__ W3,
                            const float* __restrict__ b3, const float* __restrict__ b1,
                            const float* __restrict__ bo,
                            const float* __restrict__ W1sum, const float* __restrict__ W1c,
                            const float* __restrict__ W1diffT,
                            const float* __restrict__ WoT, const ushort_t* __restrict__ W2bf,
                            float* __restrict__ out) {
    extern __shared__ char smem[];
    const int tid = threadIdx.x;
    const int bb  = blockIdx.x;
    const int w   = tid >> 6;           // wave == head
    const int l   = tid & 63;
    const int l15 = l & 15;
    const int lk  = l >> 4;

    float* scw  = (float*)(smem + SCW_OFF);
    float* c1s  = (float*)(smem + C1S_OFF);
    float* po   = (float*)(smem + PO_OFF);
    float* comb = (float*)(smem + COMB_OFF);
    float* po2  = (float*)(smem + PO2_OFF);
    const float* kb = keys + (size_t)bb * Ssz * Dsz;

    // ---- phase 0a: stage keys -> bf16 LDS (swizzled, rows >=200 zeroed) ----
    #pragma unroll
    for (int it = 0; it < 28; ++it) {          // 224 rows * 32 float4/row
        int id = tid + 256 * it;
        int row = id >> 5, c4 = id & 31;
        float4 kv = {0.f, 0.f, 0.f, 0.f};
        if (row < Ssz) kv = *(const float4*)(kb + (size_t)row * Dsz + c4 * 4);
        uint_t p0 = (uint_t)cvtbf(kv.x) | ((uint_t)cvtbf(kv.y) << 16);
        uint_t p1 = (uint_t)cvtbf(kv.z) | ((uint_t)cvtbf(kv.w) << 16);
        int off = KEYS_OFF + (((row << 8) + (c4 << 3)) ^ ((row & 7) << 4));
        *(uint_t*)(smem + off)     = p0;
        *(uint_t*)(smem + off + 4) = p1;
    }

    // ---- phase 0b: c1[n] = b1[n] + sum_j W1diffT[j][n]*q[j]  (n = tid) ----
    {
        float acc0 = b1[tid], acc1 = 0.f;
        #pragma unroll 4
        for (int j = 0; j < 128; j += 2) {
            acc0 += W1diffT[j * 256 + tid] * query[bb * 128 + j];
            acc1 += W1diffT[(j + 1) * 256 + tid] * query[bb * 128 + j + 1];
        }
        c1s[tid] = acc0 + acc1;
    }

    // ---- phase 0c: fold W1eff head-slice into registers (once, reused 7x) ----
    short8 bfr[16];                            // [t*4+nt]
    #pragma unroll
    for (int t = 0; t < 4; ++t) {
        const int k0 = t * 32 + lk * 8;
        const float4* pq = (const float4*)(query + bb * 128 + k0);
        float4 q0 = pq[0], q1 = pq[1];
        #pragma unroll
        for (int nt = 0; nt < 4; ++nt) {
            int n = w * 64 + nt * 16 + l15;
            const float4* ps = (const float4*)(W1sum + n * 128 + k0);
            const float4* pc = (const float4*)(W1c + n * 128 + k0);
            float4 s0 = ps[0], s1 = ps[1];
            float4 c0 = pc[0], c1f = pc[1];
            short8 ov;
            ov[0] = (short)cvtbf(s0.x + c0.x * q0.x);
            ov[1] = (short)cvtbf(s0.y + c0.y * q0.y);
            ov[2] = (short)cvtbf(s0.z + c0.z * q0.z);
            ov[3] = (short)cvtbf(s0.w + c0.w * q0.w);
            ov[4] = (short)cvtbf(s1.x + c1f.x * q1.x);
            ov[5] = (short)cvtbf(s1.y + c1f.y * q1.y);
            ov[6] = (short)cvtbf(s1.z + c1f.z * q1.z);
            ov[7] = (short)cvtbf(s1.w + c1f.w * q1.w);
            bfr[t * 4 + nt] = ov;
        }
    }

    // per-wave layer-2/3 constants
    const float a1v = a1[w];
    const float a2v = a2[w];
    const float b3v = b3[w];
    float b2v[2], w3v[2];
    #pragma unroll
    for (int nt = 0; nt < 2; ++nt) {
        b2v[nt] = b2[w * 32 + nt * 16 + l15];
        w3v[nt] = W3[w * 32 + nt * 16 + l15];
    }
    short8 w2f[2][2];
    #pragma unroll
    for (int kt = 0; kt < 2; ++kt)
        #pragma unroll
        for (int nt = 0; nt < 2; ++nt)
            w2f[kt][nt] = *(const short8*)(W2bf + w * 2048 + (nt * 16 + l15) * 64 + kt * 32 + lk * 8);

    __syncthreads();   // barrier 1: keys staged

    float c1v[4];
    #pragma unroll
    for (int nt = 0; nt < 4; ++nt) c1v[nt] = c1s[w * 64 + nt * 16 + l15];

    char* h1b = smem + H1S_OFF + w * 4096;     // wave-private [32][64] bf16
    const f32x4 fz = {0.f, 0.f, 0.f, 0.f};

    // ---- 7 chunks of 2 M-tiles (13 tiles); all wave-local ----
    #pragma unroll 1
    for (int c = 0; c < 7; ++c) {
        const int TT = (c == 6) ? 1 : 2;
        f32x4 acc[2][4];
        #pragma unroll
        for (int i = 0; i < 2; ++i)
            #pragma unroll
            for (int n = 0; n < 4; ++n) acc[i][n] = fz;

        #pragma unroll
        for (int t = 0; t < 4; ++t) {
            #pragma unroll
            for (int i = 0; i < 2; ++i) {
                if (i < TT) {
                    int row = (c * 2 + i) * 16 + l15;
                    int off = KEYS_OFF + (((row << 8) + (t * 64 + lk * 16)) ^ ((row & 7) << 4));
                    short8 afr = *(const short8*)(smem + off);
                    #pragma unroll
                    for (int nt = 0; nt < 4; ++nt)
                        acc[i][nt] = __builtin_amdgcn_mfma_f32_16x16x32_bf16(afr, bfr[t * 4 + nt], acc[i][nt], 0, 0, 0);
                }
            }
        }

        // leaky(h1)+c1 -> wave-private scratch (bf16, XOR-swizzled rows)
        #pragma unroll
        for (int i = 0; i < 2; ++i) {
            if (i < TT) {
                #pragma unroll
                for (int nt = 0; nt < 4; ++nt) {
                    #pragma unroll
                    for (int r = 0; r < 4; ++r) {
                        float v = acc[i][nt][r] + c1v[nt];
                        v = (v >= 0.f) ? v : a1v * v;
                        int lr = i * 16 + lk * 4 + r;
                        int colb = (nt * 16 + l15) * 2;
                        *(ushort_t*)(h1b + lr * 128 + (colb ^ ((lr & 7) << 4))) = cvtbf(v);
                    }
                }
            }
        }
        LGKM_FENCE();   // wave-private RAW

        // layer 2+3 on this chunk's rows (wave-local)
        #pragma unroll
        for (int t2 = 0; t2 < 2; ++t2) {
            if (t2 < TT) {
                f32x4 acc2[2];
                acc2[0] = fz; acc2[1] = fz;
                #pragma unroll
                for (int kt = 0; kt < 2; ++kt) {
                    int lr = t2 * 16 + l15;
                    short8 afr = *(const short8*)(h1b + lr * 128 + ((kt * 64 + lk * 16) ^ ((lr & 7) << 4)));
                    #pragma unroll
                    for (int nt = 0; nt < 2; ++nt)
                        acc2[nt] = __builtin_amdgcn_mfma_f32_16x16x32_bf16(afr, w2f[kt][nt], acc2[nt], 0, 0, 0);
                }
                #pragma unroll
                for (int r = 0; r < 4; ++r) {
                    float sum = 0.f;
                    #pragma unroll
                    for (int nt = 0; nt < 2; ++nt) {
                        float v = acc2[nt][r] + b2v[nt];
                        v = (v >= 0.f) ? v : a2v * v;
                        sum += v * w3v[nt];
                    }
                    sum += __shfl_xor(sum, 1);
                    sum += __shfl_xor(sum, 2);
                    sum += __shfl_xor(sum, 4);
                    sum += __shfl_xor(sum, 8);
                    if (l15 == 0) {
                        int sg = (c * 2 + t2) * 16 + lk * 4 + r;
                        if (sg < Ssz) {
                            float tw = __expf(0.1f * (float)(sg - (Ssz - 1)));
                            float sc = (sum + b3v) * tw;
                            scw[w * SP + sg] = kmask[bb * Ssz + sg] ? sc : -1.0e9f;
                        }
                    }
                }
            }
        }
        LGKM_FENCE();   // reads done before next chunk overwrites scratch
    }

    // ---- softmax, wave-local over this wave's head ----
    {
        float xv[4], ex[4];
        float mx = -3.0e38f;
        #pragma unroll
        for (int i = 0; i < 4; ++i) {
            int s = l + 64 * i;
            xv[i] = (s < Ssz) ? scw[w * SP + s] : -1.0e30f;
            mx = fmaxf(mx, xv[i]);
        }
        #pragma unroll
        for (int m = 1; m < 64; m <<= 1) mx = fmaxf(mx, __shfl_xor(mx, m));
        float sm = 0.f;
        #pragma unroll
        for (int i = 0; i < 4; ++i) {
            int s = l + 64 * i;
            ex[i] = (s < Ssz) ? __expf(xv[i] - mx) : 0.f;
            sm += ex[i];
        }
        #pragma unroll
        for (int m = 1; m < 64; m <<= 1) sm += __shfl_xor(sm, m);
        float inv = 1.0f / sm;
        #pragma unroll
        for (int i = 0; i < 4; ++i) {
            int s = l + 64 * i;
            if (s < Ssz) scw[w * SP + s] = ex[i] * inv;
        }
    }
    __syncthreads();   // barrier 2: weights visible; h1s now dead

    // avg_weights output
    if (tid < Ssz) {
        float aw = 0.25f * (scw[tid] + scw[SP + tid] + scw[2 * SP + tid] + scw[3 * SP + tid]);
        out[Bsz * Dsz + bb * Ssz + tid] = aw;
    }

    // ---- PV from LDS bf16 keys: wave w = head w; lane l -> d = 2l, 2l+1 ----
    {
        float s0 = 0.f, s1 = 0.f;
        #pragma unroll 4
        for (int s = 0; s < Ssz; ++s) {
            float wv = scw[w * SP + s];
            uint_t kv = *(const uint_t*)(smem + KEYS_OFF + (((s << 8) + 4 * l) ^ ((s & 7) << 4)));
            s0 += wv * bflo(kv);
            s1 += wv * bfhi(kv);
        }
        po[w * 128 + 2 * l]     = s0;
        po[w * 128 + 2 * l + 1] = s1;
    }
    __syncthreads();   // barrier 3

    if (tid < 128) comb[tid] = 0.25f * (po[tid] + po[128 + tid] + po[256 + tid] + po[384 + tid]);
    __syncthreads();   // barrier 4

    // ---- output projection: 256 threads, 2 parts of 64 j each ----
    {
        int d = tid & 127, part = tid >> 7;
        float o = 0.f;
        const float* wp = WoT + (size_t)part * 64 * 128 + d;
        #pragma unroll 8
        for (int j = 0; j < 64; ++j) o += comb[part * 64 + j] * wp[j * 128];
        po2[part * 128 + d] = o;
    }
    __syncthreads();
    if (tid < 128) out[bb * Dsz + tid] = bo[tid] + po2[tid] + po2[128 + tid];
}

// ws layout (bytes): W1sum 131072 | W1c 131072 | W1diffT 131072 | WoT 65536 | W2bf 16384
extern "C" void kernel_launch(void* const* d_in, const int* in_sizes, int n_in,
                              void* d_out, int out_size, void* d_ws, size_t ws_size,
                              hipStream_t stream) {
    const float* query = (const float*)d_in[0];
    const float* keys  = (const float*)d_in[1];
    const int*   kmask = (const int*)d_in[2];
    const float* W1    = (const float*)d_in[3];
    const float* b1    = (const float*)d_in[4];
    const float* a1    = (const float*)d_in[5];
    const float* W2    = (const float*)d_in[6];
    const float* b2    = (const float*)d_in[7];
    const float* a2    = (const float*)d_in[8];
    const float* W3    = (const float*)d_in[9];
    const float* b3    = (const float*)d_in[10];
    const float* Wo    = (const float*)d_in[11];
    const float* bo    = (const float*)d_in[12];
    float* out = (float*)d_out;

    char* ws = (char*)d_ws;
    float*    W1sum   = (float*)(ws);
    float*    W1c     = (float*)(ws + 131072);
    float*    W1diffT = (float*)(ws + 262144);
    float*    WoT     = (float*)(ws + 393216);
    ushort_t* W2bf    = (ushort_t*)(ws + 458752);

    hipFuncSetAttribute(reinterpret_cast<const void*>(attn_kernel),
                        hipFuncAttributeMaxDynamicSharedMemorySize, SMEM_BYTES);

    prep_kernel<<<128, 256, 0, stream>>>(W1, W2, Wo, W1sum, W1c, W1diffT, WoT, W2bf);
    attn_kernel<<<Bsz, 256, SMEM_BYTES, stream>>>(query, keys, kmask, a1, b2, a2, W3, b3, b1, bo,
                                                  W1sum, W1c, W1diffT, WoT, W2bf, out);
}

// Round 8
// 209.670 us; speedup vs baseline: 3.7869x; 1.0921x over previous
//
#include <hip/hip_runtime.h>
#include <hip/hip_bf16.h>
#include <stdint.h>

// Problem constants
#define Bsz 2048
#define Ssz 200
#define Dsz 128
#define SP  224

typedef __attribute__((ext_vector_type(8))) short short8;
typedef __attribute__((ext_vector_type(4))) float f32x4;
typedef unsigned short ushort_t;
typedef unsigned int uint_t;

// ---- LDS byte offsets (total 72,192 -> 2 blocks/CU) ----
#define KEYS_OFF   0        // [200][128] bf16, XOR-swizzled  51,200
#define H1S_OFF    51200    // [4 waves][2 bufs][16][64] bf16 16,384
#define SCW_OFF    67584    // [4][224] f32                    3,584
#define C1S_OFF    71168    // [256] f32                       1,024
#define SMEM_BYTES 72192
// aliases into H1S after the tile loop (h1 dead):
#define SCWB_OFF   51200    // [16][256] bf16  8,192
#define COMB_OFF   59392    // [128] f32         512
#define PO2_OFF    59904    // [2][128] f32    1,024

__device__ __forceinline__ ushort_t cvtbf(float x) {
    __hip_bfloat16 h = __float2bfloat16(x);   // RTNE; pairs into v_cvt_pk_bf16_f32
    ushort_t u;
    __builtin_memcpy(&u, &h, 2);
    return u;
}

// ---------- prep: fold W1 (sum/c/diff row-major), transpose Wo, cast W2 ----------
__global__ void prep_kernel(const float* __restrict__ W1, const float* __restrict__ W2,
                            const float* __restrict__ Wo,
                            float* __restrict__ W1sum, float* __restrict__ W1c,
                            float* __restrict__ W1diffR, float* __restrict__ WoT,
                            ushort_t* __restrict__ W2bf) {
    int i = blockIdx.x * blockDim.x + threadIdx.x;
    if (i < 32768) {                       // n in [0,256), j in [0,128)
        int n = i >> 7, j = i & 127;
        float a  = W1[n * 512 + j];        // keys part
        float dd = W1[n * 512 + 384 + j];  // (k - q) part
        W1sum[i] = a + dd;                 // coeff of k
        W1c[i]   = W1[n * 512 + 256 + j];  // coeff of k*q
        W1diffR[i] = W1[n * 512 + 128 + j] - dd;  // coeff of q (row-major)
    }
    if (i < 16384) {                       // WoT[j][d] = Wo[d][j]
        int j = i >> 7, d = i & 127;
        WoT[i] = Wo[d * 128 + j];
    }
    if (i < 8192) W2bf[i] = cvtbf(W2[i]); // flat [h][e][k], k fastest
}

// ---------- fused main kernel: 256 threads, wave = head ----------
__launch_bounds__(256, 2)
__global__ void attn_kernel(const float* __restrict__ query, const float* __restrict__ keys,
                            const int* __restrict__ kmask,
                            const float* __restrict__ a1, const float* __restrict__ b2,
                            const float* __restrict__ a2, const float* __restrict__ W3,
                            const float* __restrict__ b3, const float* __restrict__ b1,
                            const float* __restrict__ bo,
                            const float* __restrict__ W1sum, const float* __restrict__ W1c,
                            const float* __restrict__ W1diffR,
                            const float* __restrict__ WoT, const ushort_t* __restrict__ W2bf,
                            float* __restrict__ out) {
    extern __shared__ char smem[];
    const int tid = threadIdx.x;
    const int bb  = blockIdx.x;
    const int w   = tid >> 6;           // wave == head
    const int l   = tid & 63;
    const int l15 = l & 15;
    const int lk  = l >> 4;

    float* scw  = (float*)(smem + SCW_OFF);
    float* c1s  = (float*)(smem + C1S_OFF);
    float* comb = (float*)(smem + COMB_OFF);
    float* po2  = (float*)(smem + PO2_OFF);
    const float* kb = keys + (size_t)bb * Ssz * Dsz;

    // ---- phase 0a: stage keys -> bf16 LDS (swizzled), 200 rows ----
    #pragma unroll
    for (int it = 0; it < 25; ++it) {          // 200 rows * 32 float4/row
        int id = tid + 256 * it;
        int row = id >> 5, c4 = id & 31;
        float4 kv = *(const float4*)(kb + (size_t)row * Dsz + c4 * 4);
        uint2 p;
        p.x = (uint_t)cvtbf(kv.x) | ((uint_t)cvtbf(kv.y) << 16);
        p.y = (uint_t)cvtbf(kv.z) | ((uint_t)cvtbf(kv.w) << 16);
        int off = KEYS_OFF + (((row << 8) + (c4 << 3)) ^ ((row & 7) << 4));
        *(uint2*)(smem + off) = p;
    }

    // ---- phase 0b: c1[n] = b1[n] + dot(W1diffR[n], q)  (n = tid) ----
    {
        float accc = b1[tid];
        const float4* wr  = (const float4*)(W1diffR + tid * 128);
        const float4* qv4 = (const float4*)(query + bb * 128);
        #pragma unroll 8
        for (int j4 = 0; j4 < 32; ++j4) {
            float4 wv = wr[j4];
            float4 qq = qv4[j4];
            accc += wv.x * qq.x + wv.y * qq.y + wv.z * qq.z + wv.w * qq.w;
        }
        c1s[tid] = accc;
    }

    // ---- phase 0c: fold W1eff head-slice into registers (once, reused 13x) ----
    short8 bfr[16];                            // [t*4+nt]
    #pragma unroll
    for (int t = 0; t < 4; ++t) {
        const int k0 = t * 32 + lk * 8;
        const float4* pq = (const float4*)(query + bb * 128 + k0);
        float4 q0 = pq[0], q1 = pq[1];
        #pragma unroll
        for (int nt = 0; nt < 4; ++nt) {
            int n = w * 64 + nt * 16 + l15;
            const float4* ps = (const float4*)(W1sum + n * 128 + k0);
            const float4* pc = (const float4*)(W1c + n * 128 + k0);
            float4 s0 = ps[0], s1 = ps[1];
            float4 c0 = pc[0], c1f = pc[1];
            short8 ov;
            ov[0] = (short)cvtbf(s0.x + c0.x * q0.x);
            ov[1] = (short)cvtbf(s0.y + c0.y * q0.y);
            ov[2] = (short)cvtbf(s0.z + c0.z * q0.z);
            ov[3] = (short)cvtbf(s0.w + c0.w * q0.w);
            ov[4] = (short)cvtbf(s1.x + c1f.x * q1.x);
            ov[5] = (short)cvtbf(s1.y + c1f.y * q1.y);
            ov[6] = (short)cvtbf(s1.z + c1f.z * q1.z);
            ov[7] = (short)cvtbf(s1.w + c1f.w * q1.w);
            bfr[t * 4 + nt] = ov;
        }
    }

    // per-wave layer-2/3 constants
    const float a1v = a1[w];
    const float a2v = a2[w];
    const float b3v = b3[w];
    float b2v[2], w3v[2];
    #pragma unroll
    for (int nt = 0; nt < 2; ++nt) {
        b2v[nt] = b2[w * 32 + nt * 16 + l15];
        w3v[nt] = W3[w * 32 + nt * 16 + l15];
    }
    short8 w2f[2][2];
    #pragma unroll
    for (int kt = 0; kt < 2; ++kt)
        #pragma unroll
        for (int nt = 0; nt < 2; ++nt)
            w2f[kt][nt] = *(const short8*)(W2bf + w * 2048 + (nt * 16 + l15) * 64 + kt * 32 + lk * 8);

    __syncthreads();   // barrier 1: keys + c1 staged

    float c1v[4];
    #pragma unroll
    for (int nt = 0; nt < 4; ++nt) c1v[nt] = c1s[w * 64 + nt * 16 + l15];

    const f32x4 fz = {0.f, 0.f, 0.f, 0.f};
    char* h1base = smem + H1S_OFF + w * 4096;  // wave-private, 2 bufs of [16][64] bf16

    // ---- 13 tiles of 16 rows; wave-local; dbuf; compiler pipelines adjacent tiles ----
    #pragma unroll 2
    for (int m = 0; m < 13; ++m) {
        char* h1b = h1base + (m & 1) * 2048;
        f32x4 acc[4];
        #pragma unroll
        for (int nt = 0; nt < 4; ++nt) acc[nt] = fz;

        #pragma unroll
        for (int t = 0; t < 4; ++t) {
            int row = m * 16 + l15;
            row = (row < Ssz) ? row : (Ssz - 1);   // clamp tile 12; masked later
            int off = KEYS_OFF + (((row << 8) + (t * 64 + lk * 16)) ^ ((row & 7) << 4));
            short8 afr = *(const short8*)(smem + off);
            #pragma unroll
            for (int nt = 0; nt < 4; ++nt)
                acc[nt] = __builtin_amdgcn_mfma_f32_16x16x32_bf16(afr, bfr[t * 4 + nt], acc[nt], 0, 0, 0);
        }

        // leaky(h1)+c1 -> wave-private dbuf (bf16, XOR-swizzled rows)
        #pragma unroll
        for (int nt = 0; nt < 4; ++nt) {
            #pragma unroll
            for (int r = 0; r < 4; ++r) {
                float v = acc[nt][r] + c1v[nt];
                v = (v >= 0.f) ? v : a1v * v;
                int lr = lk * 4 + r;
                int colb = (nt * 16 + l15) * 2;
                *(ushort_t*)(h1b + lr * 128 + (colb ^ ((lr & 7) << 4))) = cvtbf(v);
            }
        }

        // layer 2+3 (wave-local; per-wave DS FIFO + data deps handle RAW)
        f32x4 acc2[2];
        acc2[0] = fz; acc2[1] = fz;
        #pragma unroll
        for (int kt = 0; kt < 2; ++kt) {
            short8 afr2 = *(const short8*)(h1b + l15 * 128 + ((kt * 64 + lk * 16) ^ ((l15 & 7) << 4)));
            #pragma unroll
            for (int nt = 0; nt < 2; ++nt)
                acc2[nt] = __builtin_amdgcn_mfma_f32_16x16x32_bf16(afr2, w2f[kt][nt], acc2[nt], 0, 0, 0);
        }
        #pragma unroll
        for (int r = 0; r < 4; ++r) {
            float sum = 0.f;
            #pragma unroll
            for (int nt = 0; nt < 2; ++nt) {
                float v = acc2[nt][r] + b2v[nt];
                v = (v >= 0.f) ? v : a2v * v;
                sum += v * w3v[nt];
            }
            sum += __shfl_xor(sum, 1);
            sum += __shfl_xor(sum, 2);
            sum += __shfl_xor(sum, 4);
            sum += __shfl_xor(sum, 8);
            if (l15 == 0) {
                int sg = m * 16 + lk * 4 + r;
                if (sg < Ssz) {
                    float tw = __expf(0.1f * (float)(sg - (Ssz - 1)));
                    float sc = (sum + b3v) * tw;
                    scw[w * SP + sg] = kmask[bb * Ssz + sg] ? sc : -1.0e9f;
                }
            }
        }
    }

    // ---- softmax, wave-local (reads own scw rows) ----
    float wv[4];
    {
        float xv[4];
        float mx = -3.0e38f;
        #pragma unroll
        for (int i = 0; i < 4; ++i) {
            int s = l + 64 * i;
            xv[i] = (s < Ssz) ? scw[w * SP + s] : -1.0e30f;
            mx = fmaxf(mx, xv[i]);
        }
        #pragma unroll
        for (int m = 1; m < 64; m <<= 1) mx = fmaxf(mx, __shfl_xor(mx, m));
        float sm = 0.f;
        #pragma unroll
        for (int i = 0; i < 4; ++i) {
            int s = l + 64 * i;
            wv[i] = (s < Ssz) ? __expf(xv[i] - mx) : 0.f;
            sm += wv[i];
        }
        #pragma unroll
        for (int m = 1; m < 64; m <<= 1) sm += __shfl_xor(sm, m);
        float inv = 1.0f / sm;
        #pragma unroll
        for (int i = 0; i < 4; ++i) {
            int s = l + 64 * i;
            wv[i] *= inv;
            if (s < Ssz) scw[w * SP + s] = wv[i];   // f32 weights (avg out)
        }
    }
    __syncthreads();   // barrier 2: all scw written; all h1 reads done (h1 region dead)

    // weights -> scwb bf16 [16][256] (row = head; rows 4-15 and cols >=200 zero)
    #pragma unroll
    for (int i = 0; i < 4; ++i) {
        int s = l + 64 * i;                        // covers 0..255
        *(ushort_t*)(smem + SCWB_OFF + w * 512 + s * 2) =
            (s < Ssz) ? cvtbf(wv[i]) : (ushort_t)0;
    }
    {
        uint_t* zb = (uint_t*)(smem + SCWB_OFF + 4 * 512);   // rows 4..15: 1536 u32
        #pragma unroll
        for (int k = 0; k < 6; ++k) zb[tid + 256 * k] = 0;
    }
    __syncthreads();   // barrier 3: scwb ready

    // avg_weights output
    if (tid < Ssz) {
        float aw = 0.25f * (scw[tid] + scw[SP + tid] + scw[2 * SP + tid] + scw[3 * SP + tid]);
        out[Bsz * Dsz + bb * Ssz + tid] = aw;
    }

    // ---- PV via MFMA: A = scwb (rows=heads), B = keys; wave w -> d cols [32w, 32w+32) ----
    {
        f32x4 acc4a = fz, acc4b = fz;
        #pragma unroll
        for (int t7 = 0; t7 < 7; ++t7) {
            int kbase = t7 * 32 + lk * 8;
            short8 afr = *(const short8*)(smem + SCWB_OFF + l15 * 512 + kbase * 2);
            short8 b2a, b2b;
            #pragma unroll
            for (int j = 0; j < 8; ++j) {
                int s = kbase + j;
                ushort_t kva = 0, kvb = 0;
                if (s < Ssz) {
                    int rowoff = KEYS_OFF + (s << 8);
                    int sw = (s & 7) << 4;
                    kva = *(const ushort_t*)(smem + (rowoff + ((32 * w + l15) << 1) ^ sw));
                    kvb = *(const ushort_t*)(smem + (rowoff + ((32 * w + 16 + l15) << 1) ^ sw));
                }
                b2a[j] = (short)kva;
                b2b[j] = (short)kvb;
            }
            acc4a = __builtin_amdgcn_mfma_f32_16x16x32_bf16(afr, b2a, acc4a, 0, 0, 0);
            acc4b = __builtin_amdgcn_mfma_f32_16x16x32_bf16(afr, b2b, acc4b, 0, 0, 0);
        }
        if (lk == 0) {
            comb[32 * w + l15]      = 0.25f * (acc4a[0] + acc4a[1] + acc4a[2] + acc4a[3]);
            comb[32 * w + 16 + l15] = 0.25f * (acc4b[0] + acc4b[1] + acc4b[2] + acc4b[3]);
        }
    }
    __syncthreads();   // barrier 4: comb ready

    // ---- output projection: 256 threads, 2 parts of 64 j each ----
    {
        int d = tid & 127, part = tid >> 7;
        float o = 0.f;
        const float* wp = WoT + (size_t)part * 64 * 128 + d;
        #pragma unroll 8
        for (int j = 0; j < 64; ++j) o += comb[part * 64 + j] * wp[j * 128];
        po2[part * 128 + d] = o;
    }
    __syncthreads();   // barrier 5
    if (tid < 128) out[bb * Dsz + tid] = bo[tid] + po2[tid] + po2[128 + tid];
}

// ws layout (bytes): W1sum 131072 | W1c 131072 | W1diffR 131072 | WoT 65536 | W2bf 16384
extern "C" void kernel_launch(void* const* d_in, const int* in_sizes, int n_in,
                              void* d_out, int out_size, void* d_ws, size_t ws_size,
                              hipStream_t stream) {
    const float* query = (const float*)d_in[0];
    const float* keys  = (const float*)d_in[1];
    const int*   kmask = (const int*)d_in[2];
    const float* W1    = (const float*)d_in[3];
    const float* b1    = (const float*)d_in[4];
    const float* a1    = (const float*)d_in[5];
    const float* W2    = (const float*)d_in[6];
    const float* b2    = (const float*)d_in[7];
    const float* a2    = (const float*)d_in[8];
    const float* W3    = (const float*)d_in[9];
    const float* b3    = (const float*)d_in[10];
    const float* Wo    = (const float*)d_in[11];
    const float* bo    = (const float*)d_in[12];
    float* out = (float*)d_out;

    char* ws = (char*)d_ws;
    float*    W1sum   = (float*)(ws);
    float*    W1c     = (float*)(ws + 131072);
    float*    W1diffR = (float*)(ws + 262144);
    float*    WoT     = (float*)(ws + 393216);
    ushort_t* W2bf    = (ushort_t*)(ws + 458752);

    hipFuncSetAttribute(reinterpret_cast<const void*>(attn_kernel),
                        hipFuncAttributeMaxDynamicSharedMemorySize, SMEM_BYTES);

    prep_kernel<<<128, 256, 0, stream>>>(W1, W2, Wo, W1sum, W1c, W1diffR, WoT, W2bf);
    attn_kernel<<<Bsz, 256, SMEM_BYTES, stream>>>(query, keys, kmask, a1, b2, a2, W3, b3, b1, bo,
                                                  W1sum, W1c, W1diffR, WoT, W2bf, out);
}